// Round 7
// baseline (227.298 us; speedup 1.0000x reference)
//
#include <hip/hip_runtime.h>
#include <math.h>

// VQ-VAE quantize: z [32,8,16,16] f32, codebook [16384,8] f32
// N=8192 rows, K=16384 codes, D=8.
// Outputs (concatenated f32): z_q [65536], loss [1], idx-as-float [8192].
//
// f[n,k] = 200*dot(z_n,e_k) - 100*||e_k||^2  (= -d/T + row const; softmax &
// argmax shift-invariant). exp underflows for f - m < -87 (matches fp32 ref).
//
// R7. R6 spilled (WRITE_SIZE 77MB = scratch): 16 rows/THREAD needs 128 VGPR
// for zr alone. Session data (R0=143 R1=97 R3=143 R6=150) says perf needs
// BOTH rows/wave=4 intensity AND "convoys" (multiple waves sweeping the
// SAME k-sequence: lead wave misses to L2, followers hit L1). R1 = 2
// convoys/CU of 4 waves, 2 waves/SIMD, latency-bound at 3x its L1 floor.
//
// This version: 512-thr blocks = 8 waves = {4 row-groups} x {2 K-halves}.
// Each wave: 4 rows in regs (R1's ~88 VGPR footprint), sweeps its half of
// K (128 k-iters). The 4 same-half waves form a convoy. Grid 512 x 8 =
// 4096 waves = 4 waves/SIMD (2x R1). Per-row candidate lists in LDS are
// appended by the row's 2 half-waves (atomics; merge correctness proven in
// R3); running-max exchanged with partner wave (wave^4) every 2048 codes
// (load-bearing: keeps candidate counts << CAP). Flush: each wave does 2
// rows. bk[] precomputed + fmaf-chain dot -> bitwise-identical f at every
// site (R6 determinism fix); kmin==INT_MAX safety net -> wave-parallel
// resweep (~5us) instead of garbage.
// __launch_bounds__(512,4) pins VGPR <= 128 (4 waves/SIMD step).

#define KCODES 16384
#define CAP 192

__device__ __forceinline__ float dot8s(const float (&z)[8], float4 c0,
                                       float4 c1, float b) {
    float a = fmaf(z[0], c0.x, b);
    a = fmaf(z[1], c0.y, a);
    a = fmaf(z[2], c0.z, a);
    a = fmaf(z[3], c0.w, a);
    a = fmaf(z[4], c1.x, a);
    a = fmaf(z[5], c1.y, a);
    a = fmaf(z[6], c1.z, a);
    a = fmaf(z[7], c1.w, a);
    return a;
}

// ---------------- prep: codebook norms + workspace zeroing ----------------
__global__ __launch_bounds__(256) void prep_cb(const float* __restrict__ cb,
                                               float* __restrict__ bk,
                                               float* __restrict__ avgp,
                                               float* __restrict__ scal) {
    int k = blockIdx.x * 256 + threadIdx.x;
    const float4* c4 = (const float4*)cb;
    float4 c0 = c4[2 * k], c1 = c4[2 * k + 1];
    float nrm = c0.x * c0.x + c0.y * c0.y + c0.z * c0.z + c0.w * c0.w
              + c1.x * c1.x + c1.y * c1.y + c1.z * c1.z + c1.w * c1.w;
    bk[k] = -100.0f * nrm;
    avgp[k] = 0.0f;              // ws is poisoned each launch: zero it here
    if (k < 8)    scal[k] = 0.0f;
}

// ---------------- pass 1: 16 rows/block, 8 waves = 4 groups x 2 K-halves ----
// Wave w = h*4+g: row-group g (4 rows), K-half h. Grid 512 blocks x 512 thr.
__global__ __launch_bounds__(512, 4) void pass1(
    const float* __restrict__ z, const float* __restrict__ cb,
    const float* __restrict__ bk, float* __restrict__ out_zq,
    float* __restrict__ out_idx, float* __restrict__ scal,
    float* __restrict__ avgp)
{
    __shared__ float wfb[16][CAP];
    __shared__ int   wkb[16][CAP];
    __shared__ int   cnt[16];
    __shared__ float sm[8][4];          // partner-wave max exchange

    const int wave = threadIdx.x >> 6;  // 0..7
    const int lane = threadIdx.x & 63;
    const int g    = wave & 3;          // row-group
    const int h    = wave >> 2;         // K-half
    const int lrow0 = g * 4;            // block-local first row of group
    const int row0 = blockIdx.x * 16 + lrow0;
    const int kbase = h * 8192;         // this wave's half of the codebook

    // load this group's 4 rows (lane-uniform -> mostly SGPRs), fold 200x in
    float zr[4][8];
#pragma unroll
    for (int r = 0; r < 4; ++r) {
        int row = row0 + r;
        const float* p = z + (row >> 8) * 2048 + (row & 255);
#pragma unroll
        for (int c = 0; c < 8; ++c) zr[r][c] = 200.0f * p[c * 256];
    }
    if (threadIdx.x < 16) cnt[threadIdx.x] = 0;
    __syncthreads();

    const float4* c4 = (const float4*)cb;
    float m[4], mt[4];
#pragma unroll
    for (int r = 0; r < 4; ++r) m[r] = -3.4e38f;

    // intra-wave reduce + partner-wave exchange -> m[] = running max over
    // both K-halves for this row-group
    auto exchange = [&]() {
#pragma unroll
        for (int off = 32; off; off >>= 1) {
#pragma unroll
            for (int r = 0; r < 4; ++r)
                m[r] = fmaxf(m[r], __shfl_xor(m[r], off));
        }
        if (lane == 0) {
#pragma unroll
            for (int r = 0; r < 4; ++r) sm[wave][r] = m[r];
        }
        __syncthreads();
#pragma unroll
        for (int r = 0; r < 4; ++r)
            m[r] = fmaxf(m[r], sm[wave ^ 4][r]);
        __syncthreads();                 // sm reused next round
#pragma unroll
        for (int r = 0; r < 4; ++r) mt[r] = m[r] - 87.0f;
    };

    // warm-up: first 512 codes of own half, max only (threshold priming;
    // these codes are RE-SWEPT below -- coverage must be total)
#pragma unroll 1
    for (int j = 0; j < 8; ++j) {
        int k = kbase + lane + 64 * j;
        float4 c0 = c4[2 * k], c1 = c4[2 * k + 1];
        float b = bk[k];
#pragma unroll
        for (int r = 0; r < 4; ++r)
            m[r] = fmaxf(m[r], dot8s(zr[r], c0, c1, b));
    }
    exchange();

    // ---- main sweep: ALL 128 k-iters of own half, ping-pong prefetch ----
    float4 A0, A1, B0, B1; float Ab, Bb;
    auto loadA = [&](int j) { int k = kbase + lane + 64 * j;
                              A0 = c4[2 * k]; A1 = c4[2 * k + 1]; Ab = bk[k]; };
    auto loadB = [&](int j) { int k = kbase + lane + 64 * j;
                              B0 = c4[2 * k]; B1 = c4[2 * k + 1]; Bb = bk[k]; };

    // fast path per k: 32 FMA + 4 cmp; rare work behind wave-uniform __any
    auto comp = [&](int j, float4 c0, float4 c1, float b) {
        const int k = kbase + lane + 64 * j;
        float f0 = dot8s(zr[0], c0, c1, b);
        float f1 = dot8s(zr[1], c0, c1, b);
        float f2 = dot8s(zr[2], c0, c1, b);
        float f3 = dot8s(zr[3], c0, c1, b);
        bool h0 = f0 > mt[0], h1 = f1 > mt[1];
        bool h2 = f2 > mt[2], h3 = f3 > mt[3];
        if (__any(h0 | h1 | h2 | h3)) {      // wave-uniform, rare
            if (h0) { m[0] = fmaxf(m[0], f0); mt[0] = m[0] - 87.0f;
                int s_ = atomicAdd(&cnt[lrow0 + 0], 1);
                if (s_ < CAP) { wfb[lrow0 + 0][s_] = f0; wkb[lrow0 + 0][s_] = k; } }
            if (h1) { m[1] = fmaxf(m[1], f1); mt[1] = m[1] - 87.0f;
                int s_ = atomicAdd(&cnt[lrow0 + 1], 1);
                if (s_ < CAP) { wfb[lrow0 + 1][s_] = f1; wkb[lrow0 + 1][s_] = k; } }
            if (h2) { m[2] = fmaxf(m[2], f2); mt[2] = m[2] - 87.0f;
                int s_ = atomicAdd(&cnt[lrow0 + 2], 1);
                if (s_ < CAP) { wfb[lrow0 + 2][s_] = f2; wkb[lrow0 + 2][s_] = k; } }
            if (h3) { m[3] = fmaxf(m[3], f3); mt[3] = m[3] - 87.0f;
                int s_ = atomicAdd(&cnt[lrow0 + 3], 1);
                if (s_ < CAP) { wfb[lrow0 + 3][s_] = f3; wkb[lrow0 + 3][s_] = k; } }
        }
    };

    loadA(0);                                   // prime the pipeline
#pragma unroll 1
    for (int t = 0; t < 4; ++t) {               // 4 chunks of 32 k-iters
#pragma unroll 1
        for (int p = 0; p < 16; ++p) {
            const int j = t * 32 + p * 2;
            loadB(j + 1);
            comp(j, A0, A1, Ab);
            loadA((j + 2) & 127);               // t=3,p=15 wraps (harmless)
            comp(j + 1, B0, B1, Bb);
        }
        exchange();   // after last chunk: m[] = TRUE global max (both halves)
    }
    __syncthreads();   // all waves' candidate writes/atomics visible

    // flush: wave (g,h) flushes block-local rows lrow0+2h, lrow0+2h+1
    float entAcc = 0.0f, sqAcc = 0.0f;
#pragma unroll 1
    for (int rr = 0; rr < 2; ++rr) {
        const int lg  = 2 * h + rr;          // 0..3 within group
        const int lr  = lrow0 + lg;          // block-local list index
        const int row = blockIdx.x * 16 + lr;
        const float mm = m[lg];
        const int c = cnt[lr];

        float sl = 0.0f, tl = 0.0f;
        int kmin = 0x7fffffff;
        bool ok = (c <= CAP);

        if (ok) {
            // ---- normal: stats from the recorded candidates ----
            for (int i = lane; i < c; i += 64) {
                float x = wfb[lr][i] - mm;   // <= 0; == 0 at the argmax
                float e = 0.0f;
                if (x > -87.0f) {
                    e = __expf(x);
                    sl += e;
                    tl = fmaf(x, e, tl);
                    if (x == 0.0f) kmin = min(kmin, wkb[lr][i]);
                }
                wfb[lr][i] = e;              // stash e for the avgp loop
            }
#pragma unroll
            for (int off = 32; off; off >>= 1) {
                sl += __shfl_xor(sl, off);
                tl += __shfl_xor(tl, off);
                kmin = min(kmin, __shfl_xor(kmin, off));
            }
            ok = (kmin != 0x7fffffff);       // argmax found? (safety net)
        }

        if (!ok) {
            // ---- overflow / argmax-miss: wave-parallel FULL-K resweep ----
            sl = 0.0f; tl = 0.0f; kmin = 0x7fffffff;
            for (int k = lane; k < KCODES; k += 64) {
                float f = dot8s(zr[lg], c4[2 * k], c4[2 * k + 1], bk[k]);
                float x = f - mm;
                if (x > -87.0f) {
                    float e = __expf(x);
                    sl += e; tl = fmaf(x, e, tl);
                    if (x == 0.0f) kmin = min(kmin, k);
                }
            }
#pragma unroll
            for (int off = 32; off; off >>= 1) {
                sl += __shfl_xor(sl, off);
                tl += __shfl_xor(tl, off);
                kmin = min(kmin, __shfl_xor(kmin, off));
            }
            float rs = 1.0f / sl;
            for (int k = lane; k < KCODES; k += 64) {
                float f = dot8s(zr[lg], c4[2 * k], c4[2 * k + 1], bk[k]);
                float x = f - mm;
                if (x > -87.0f) atomicAdd(&avgp[k], __expf(x) * rs);
            }
        } else {
            float rs = 1.0f / sl;
            for (int i = lane; i < c; i += 64) {
                float e = wfb[lr][i];
                if (e != 0.0f) atomicAdd(&avgp[wkb[lr][i]], e * rs);
            }
        }

        if (lane == 0) {
            float rs = 1.0f / sl;
            entAcc += tl * rs - logf(sl);
            out_idx[row] = (float)kmin;
            float4 q0 = c4[2 * kmin], q1 = c4[2 * kmin + 1];
            float qv[8] = {q0.x, q0.y, q0.z, q0.w, q1.x, q1.y, q1.z, q1.w};
            int bb = row >> 8, hw = row & 255;
            const float* zraw = z + bb * 2048 + hw;   // raw row (L1-hot)
            float* o = out_zq + bb * 2048 + hw;
#pragma unroll
            for (int ch = 0; ch < 8; ++ch) {
                float raw = zraw[ch * 256];
                o[ch * 256] = qv[ch];
                float dq = qv[ch] - raw;
                sqAcc += dq * dq;
            }
        }
    }
    if (lane == 0) {
        atomicAdd(&scal[0], sqAcc);
        atomicAdd(&scal[1], entAcc);
    }
}

// ---------------- finalize: avg entropy + loss assembly ----------------
__global__ __launch_bounds__(256) void finalize(
    const float* __restrict__ avgp, const float* __restrict__ scal,
    float* __restrict__ out_loss)
{
    float acc = 0.0f;
    for (int k = threadIdx.x; k < KCODES; k += 256) {
        float avg = avgp[k] * (1.0f / 8192.0f);
        acc += avg * logf(avg + 1e-5f);    // avg==0 contributes exactly 0
    }
#pragma unroll
    for (int off = 32; off > 0; off >>= 1) acc += __shfl_xor(acc, off);
    __shared__ float red[4];
    int wave = threadIdx.x >> 6, lane = threadIdx.x & 63;
    if (lane == 0) red[wave] = acc;
    __syncthreads();
    if (threadIdx.x == 0) {
        float T = red[0] + red[1] + red[2] + red[3];   // sum avg*log(avg+eps)
        // loss = 1.25*mean((zq-z)^2) + 0.1*(sample_entropy - avg_entropy)
        float loss = 1.25f * (scal[0] * (1.0f / 65536.0f))
                   + 0.1f * (T - scal[1] * (1.0f / 8192.0f));
        out_loss[0] = loss;
    }
}

extern "C" void kernel_launch(void* const* d_in, const int* in_sizes, int n_in,
                              void* d_out, int out_size, void* d_ws, size_t ws_size,
                              hipStream_t stream) {
    const float* z  = (const float*)d_in[0];   // [32,8,16,16]
    const float* cb = (const float*)d_in[1];   // [16384,8]
    float* out = (float*)d_out;
    float* ws  = (float*)d_ws;

    // workspace layout (floats)
    float* bk   = ws;                // 16384 : -100*||e_k||^2
    float* avgp = ws + 16384;        // 16384 : sum_n p[n,k]
    float* scal = ws + 32768;        // 2     : [sq, entS]  (+6 pad)

    float* out_zq   = out;           // 65536
    float* out_loss = out + 65536;   // 1
    float* out_idx  = out + 65537;   // 8192

    // prep_cb zeroes avgp/scal (ws is re-poisoned every launch)
    prep_cb <<<64,  256, 0, stream>>>(cb, bk, avgp, scal);
    pass1   <<<512, 512, 0, stream>>>(z, cb, bk, out_zq, out_idx, scal, avgp);
    finalize<<<1,   256, 0, stream>>>(avgp, scal, out_loss);
}

// Round 9
// 222.881 us; speedup vs baseline: 1.0198x; 1.0198x over previous
//
#include <hip/hip_runtime.h>
#include <math.h>

// VQ-VAE quantize: z [32,8,16,16] f32, codebook [16384,8] f32
// N=8192 rows, K=16384 codes, D=8.
// Outputs (concatenated f32): z_q [65536], loss [1], idx-as-float [8192].
//
// f[n,k] = 200*dot(z_n,e_k) - 100*||e_k||^2  (= -d/T + row const; softmax &
// argmax shift-invariant). exp underflows for f - m < -87 (matches fp32 ref).
//
// R9 = R8 resubmitted verbatim (R8 bench was an infra failure: container
// died before compile/run; the experiment never executed).
//
// R8 fix of R7's 36MB-scratch spill: R7's flush indexed zr[lg] with
// RUNTIME lg=2*h+rr -> compiler demoted zr[4][8] to scratch (rule: runtime-
// indexed register arrays go to local memory), VGPR=44 + 33MB spill traffic,
// VALUBusy 26%. Fix: flush is split on the wave-uniform h into two
// statically-indexed branches (zr[0]/zr[1]/m[0]/m[1] vs zr[2]/zr[3]/m[2]/
// m[3] as literals via a flushRow(const float(&)[8],...) helper). No other
// change from R7.
//
// Structure: 512-thr blocks = 8 waves = {4 row-groups} x {2 K-halves}.
// Each wave: 4 rows in regs, sweeps its K-half (128 k-iters). Same-half
// waves form a convoy (same k-sequence; lead wave misses to L2, followers
// hit L1) KEPT ALIGNED by the exchange barriers every 2048 codes (this is
// why R3's cross-block convoys failed: no sync -> drift > L1 capacity).
// Grid 512 x 8 = 4096 waves = 4 waves/SIMD. Per-row candidate lists in LDS
// appended by the row's 2 half-waves (atomics; merge proven R3). bk[]
// precomputed + fmaf-chain dot -> bitwise-identical f at every site (R6
// determinism fix); kmin==INT_MAX / overflow safety net -> wave-parallel
// full-K resweep (~5us) instead of garbage.

#define KCODES 16384
#define CAP 192

__device__ __forceinline__ float dot8s(const float (&z)[8], float4 c0,
                                       float4 c1, float b) {
    float a = fmaf(z[0], c0.x, b);
    a = fmaf(z[1], c0.y, a);
    a = fmaf(z[2], c0.z, a);
    a = fmaf(z[3], c0.w, a);
    a = fmaf(z[4], c1.x, a);
    a = fmaf(z[5], c1.y, a);
    a = fmaf(z[6], c1.z, a);
    a = fmaf(z[7], c1.w, a);
    return a;
}

// ---------------- prep: codebook norms + workspace zeroing ----------------
__global__ __launch_bounds__(256) void prep_cb(const float* __restrict__ cb,
                                               float* __restrict__ bk,
                                               float* __restrict__ avgp,
                                               float* __restrict__ scal) {
    int k = blockIdx.x * 256 + threadIdx.x;
    const float4* c4 = (const float4*)cb;
    float4 c0 = c4[2 * k], c1 = c4[2 * k + 1];
    float nrm = c0.x * c0.x + c0.y * c0.y + c0.z * c0.z + c0.w * c0.w
              + c1.x * c1.x + c1.y * c1.y + c1.z * c1.z + c1.w * c1.w;
    bk[k] = -100.0f * nrm;
    avgp[k] = 0.0f;              // ws is poisoned each launch: zero it here
    if (k < 8)    scal[k] = 0.0f;
}

// ---------------- pass 1: 16 rows/block, 8 waves = 4 groups x 2 K-halves ----
// Wave w = h*4+g: row-group g (4 rows), K-half h. Grid 512 blocks x 512 thr.
__global__ __launch_bounds__(512, 4) void pass1(
    const float* __restrict__ z, const float* __restrict__ cb,
    const float* __restrict__ bk, float* __restrict__ out_zq,
    float* __restrict__ out_idx, float* __restrict__ scal,
    float* __restrict__ avgp)
{
    __shared__ float wfb[16][CAP];
    __shared__ int   wkb[16][CAP];
    __shared__ int   cnt[16];
    __shared__ float sm[8][4];          // partner-wave max exchange

    const int wave = threadIdx.x >> 6;  // 0..7
    const int lane = threadIdx.x & 63;
    const int g    = wave & 3;          // row-group
    const int h    = wave >> 2;         // K-half
    const int lrow0 = g * 4;            // block-local first row of group
    const int row0 = blockIdx.x * 16 + lrow0;
    const int kbase = h * 8192;         // this wave's half of the codebook

    // load this group's 4 rows, fold the 200x scale in (static indexing ONLY)
    float zr[4][8];
#pragma unroll
    for (int r = 0; r < 4; ++r) {
        int row = row0 + r;
        const float* p = z + (row >> 8) * 2048 + (row & 255);
#pragma unroll
        for (int c = 0; c < 8; ++c) zr[r][c] = 200.0f * p[c * 256];
    }
    if (threadIdx.x < 16) cnt[threadIdx.x] = 0;
    __syncthreads();

    const float4* c4 = (const float4*)cb;
    float m[4], mt[4];
#pragma unroll
    for (int r = 0; r < 4; ++r) m[r] = -3.4e38f;

    // intra-wave reduce + partner-wave exchange -> m[] = running max over
    // both K-halves for this row-group
    auto exchange = [&]() {
#pragma unroll
        for (int off = 32; off; off >>= 1) {
#pragma unroll
            for (int r = 0; r < 4; ++r)
                m[r] = fmaxf(m[r], __shfl_xor(m[r], off));
        }
        if (lane == 0) {
#pragma unroll
            for (int r = 0; r < 4; ++r) sm[wave][r] = m[r];
        }
        __syncthreads();
#pragma unroll
        for (int r = 0; r < 4; ++r)
            m[r] = fmaxf(m[r], sm[wave ^ 4][r]);
        __syncthreads();                 // sm reused next round
#pragma unroll
        for (int r = 0; r < 4; ++r) mt[r] = m[r] - 87.0f;
    };

    // warm-up: first 512 codes of own half, max only (threshold priming;
    // these codes are RE-SWEPT below -- coverage must be total)
#pragma unroll 1
    for (int j = 0; j < 8; ++j) {
        int k = kbase + lane + 64 * j;
        float4 c0 = c4[2 * k], c1 = c4[2 * k + 1];
        float b = bk[k];
#pragma unroll
        for (int r = 0; r < 4; ++r)
            m[r] = fmaxf(m[r], dot8s(zr[r], c0, c1, b));
    }
    exchange();

    // ---- main sweep: ALL 128 k-iters of own half, ping-pong prefetch ----
    float4 A0, A1, B0, B1; float Ab, Bb;
    auto loadA = [&](int j) { int k = kbase + lane + 64 * j;
                              A0 = c4[2 * k]; A1 = c4[2 * k + 1]; Ab = bk[k]; };
    auto loadB = [&](int j) { int k = kbase + lane + 64 * j;
                              B0 = c4[2 * k]; B1 = c4[2 * k + 1]; Bb = bk[k]; };

    // fast path per k: 32 FMA + 4 cmp; rare work behind wave-uniform __any
    auto comp = [&](int j, float4 c0, float4 c1, float b) {
        const int k = kbase + lane + 64 * j;
        float f0 = dot8s(zr[0], c0, c1, b);
        float f1 = dot8s(zr[1], c0, c1, b);
        float f2 = dot8s(zr[2], c0, c1, b);
        float f3 = dot8s(zr[3], c0, c1, b);
        bool h0 = f0 > mt[0], h1 = f1 > mt[1];
        bool h2 = f2 > mt[2], h3 = f3 > mt[3];
        if (__any(h0 | h1 | h2 | h3)) {      // wave-uniform, rare
            if (h0) { m[0] = fmaxf(m[0], f0); mt[0] = m[0] - 87.0f;
                int s_ = atomicAdd(&cnt[lrow0 + 0], 1);
                if (s_ < CAP) { wfb[lrow0 + 0][s_] = f0; wkb[lrow0 + 0][s_] = k; } }
            if (h1) { m[1] = fmaxf(m[1], f1); mt[1] = m[1] - 87.0f;
                int s_ = atomicAdd(&cnt[lrow0 + 1], 1);
                if (s_ < CAP) { wfb[lrow0 + 1][s_] = f1; wkb[lrow0 + 1][s_] = k; } }
            if (h2) { m[2] = fmaxf(m[2], f2); mt[2] = m[2] - 87.0f;
                int s_ = atomicAdd(&cnt[lrow0 + 2], 1);
                if (s_ < CAP) { wfb[lrow0 + 2][s_] = f2; wkb[lrow0 + 2][s_] = k; } }
            if (h3) { m[3] = fmaxf(m[3], f3); mt[3] = m[3] - 87.0f;
                int s_ = atomicAdd(&cnt[lrow0 + 3], 1);
                if (s_ < CAP) { wfb[lrow0 + 3][s_] = f3; wkb[lrow0 + 3][s_] = k; } }
        }
    };

    loadA(0);                                   // prime the pipeline
#pragma unroll 1
    for (int t = 0; t < 4; ++t) {               // 4 chunks of 32 k-iters
#pragma unroll 1
        for (int p = 0; p < 16; ++p) {
            const int j = t * 32 + p * 2;
            loadB(j + 1);
            comp(j, A0, A1, Ab);
            loadA((j + 2) & 127);               // t=3,p=15 wraps (harmless)
            comp(j + 1, B0, B1, Bb);
        }
        exchange();   // after last chunk: m[] = TRUE global max (both halves)
    }
    __syncthreads();   // all waves' candidate writes/atomics visible

    // flush: wave (g,h) flushes block-local rows lrow0+2h, lrow0+2h+1.
    // STATIC zr/m indexing via wave-uniform branch (rule #20: runtime index
    // would demote zr to scratch -- R7's 36MB-spill bug).
    float entAcc = 0.0f, sqAcc = 0.0f;

    auto flushRow = [&](const float (&zz)[8], float mm, int lr, int row) {
        const int c = cnt[lr];
        float sl = 0.0f, tl = 0.0f;
        int kmin = 0x7fffffff;
        bool ok = (c <= CAP);

        if (ok) {
            // ---- normal: stats from the recorded candidates ----
            for (int i = lane; i < c; i += 64) {
                float x = wfb[lr][i] - mm;   // <= 0; == 0 at the argmax
                float e = 0.0f;
                if (x > -87.0f) {
                    e = __expf(x);
                    sl += e;
                    tl = fmaf(x, e, tl);
                    if (x == 0.0f) kmin = min(kmin, wkb[lr][i]);
                }
                wfb[lr][i] = e;              // stash e for the avgp loop
            }
#pragma unroll
            for (int off = 32; off; off >>= 1) {
                sl += __shfl_xor(sl, off);
                tl += __shfl_xor(tl, off);
                kmin = min(kmin, __shfl_xor(kmin, off));
            }
            ok = (kmin != 0x7fffffff);       // argmax found? (safety net)
        }

        if (!ok) {
            // ---- overflow / argmax-miss: wave-parallel FULL-K resweep ----
            sl = 0.0f; tl = 0.0f; kmin = 0x7fffffff;
            for (int k = lane; k < KCODES; k += 64) {
                float f = dot8s(zz, c4[2 * k], c4[2 * k + 1], bk[k]);
                float x = f - mm;
                if (x > -87.0f) {
                    float e = __expf(x);
                    sl += e; tl = fmaf(x, e, tl);
                    if (x == 0.0f) kmin = min(kmin, k);
                }
            }
#pragma unroll
            for (int off = 32; off; off >>= 1) {
                sl += __shfl_xor(sl, off);
                tl += __shfl_xor(tl, off);
                kmin = min(kmin, __shfl_xor(kmin, off));
            }
            float rs = 1.0f / sl;
            for (int k = lane; k < KCODES; k += 64) {
                float f = dot8s(zz, c4[2 * k], c4[2 * k + 1], bk[k]);
                float x = f - mm;
                if (x > -87.0f) atomicAdd(&avgp[k], __expf(x) * rs);
            }
        } else {
            float rs = 1.0f / sl;
            for (int i = lane; i < c; i += 64) {
                float e = wfb[lr][i];
                if (e != 0.0f) atomicAdd(&avgp[wkb[lr][i]], e * rs);
            }
        }

        if (lane == 0) {
            float rs = 1.0f / sl;
            entAcc += tl * rs - logf(sl);
            out_idx[row] = (float)kmin;
            float4 q0 = c4[2 * kmin], q1 = c4[2 * kmin + 1];
            float qv[8] = {q0.x, q0.y, q0.z, q0.w, q1.x, q1.y, q1.z, q1.w};
            int bb = row >> 8, hw = row & 255;
            const float* zraw = z + bb * 2048 + hw;   // raw row (L1-hot)
            float* o = out_zq + bb * 2048 + hw;
#pragma unroll
            for (int ch = 0; ch < 8; ++ch) {
                float raw = zraw[ch * 256];
                o[ch * 256] = qv[ch];
                float dq = qv[ch] - raw;
                sqAcc += dq * dq;
            }
        }
    };

    if (h == 0) {            // wave-uniform branch; all indices literal
        flushRow(zr[0], m[0], lrow0 + 0, row0 + 0);
        flushRow(zr[1], m[1], lrow0 + 1, row0 + 1);
    } else {
        flushRow(zr[2], m[2], lrow0 + 2, row0 + 2);
        flushRow(zr[3], m[3], lrow0 + 3, row0 + 3);
    }

    if (lane == 0) {
        atomicAdd(&scal[0], sqAcc);
        atomicAdd(&scal[1], entAcc);
    }
}

// ---------------- finalize: avg entropy + loss assembly ----------------
__global__ __launch_bounds__(256) void finalize(
    const float* __restrict__ avgp, const float* __restrict__ scal,
    float* __restrict__ out_loss)
{
    float acc = 0.0f;
    for (int k = threadIdx.x; k < KCODES; k += 256) {
        float avg = avgp[k] * (1.0f / 8192.0f);
        acc += avg * logf(avg + 1e-5f);    // avg==0 contributes exactly 0
    }
#pragma unroll
    for (int off = 32; off > 0; off >>= 1) acc += __shfl_xor(acc, off);
    __shared__ float red[4];
    int wave = threadIdx.x >> 6, lane = threadIdx.x & 63;
    if (lane == 0) red[wave] = acc;
    __syncthreads();
    if (threadIdx.x == 0) {
        float T = red[0] + red[1] + red[2] + red[3];   // sum avg*log(avg+eps)
        // loss = 1.25*mean((zq-z)^2) + 0.1*(sample_entropy - avg_entropy)
        float loss = 1.25f * (scal[0] * (1.0f / 65536.0f))
                   + 0.1f * (T - scal[1] * (1.0f / 8192.0f));
        out_loss[0] = loss;
    }
}

extern "C" void kernel_launch(void* const* d_in, const int* in_sizes, int n_in,
                              void* d_out, int out_size, void* d_ws, size_t ws_size,
                              hipStream_t stream) {
    const float* z  = (const float*)d_in[0];   // [32,8,16,16]
    const float* cb = (const float*)d_in[1];   // [16384,8]
    float* out = (float*)d_out;
    float* ws  = (float*)d_ws;

    // workspace layout (floats)
    float* bk   = ws;                // 16384 : -100*||e_k||^2
    float* avgp = ws + 16384;        // 16384 : sum_n p[n,k]
    float* scal = ws + 32768;        // 2     : [sq, entS]  (+6 pad)

    float* out_zq   = out;           // 65536
    float* out_loss = out + 65536;   // 1
    float* out_idx  = out + 65537;   // 8192

    // prep_cb zeroes avgp/scal (ws is re-poisoned every launch)
    prep_cb <<<64,  256, 0, stream>>>(cb, bk, avgp, scal);
    pass1   <<<512, 512, 0, stream>>>(z, cb, bk, out_zq, out_idx, scal, avgp);
    finalize<<<1,   256, 0, stream>>>(avgp, scal, out_loss);
}

// Round 10
// 154.210 us; speedup vs baseline: 1.4740x; 1.4453x over previous
//
#include <hip/hip_runtime.h>
#include <math.h>

// VQ-VAE quantize: z [32,8,16,16] f32, codebook [16384,8] f32
// N=8192 rows, K=16384 codes, D=8.
// Outputs (concatenated f32): z_q [65536], loss [1], idx-as-float [8192].
//
// f[n,k] = 200*dot(z_n,e_k) - 100*||e_k||^2  (= -d/T + row const; softmax &
// argmax shift-invariant). exp underflows for f - m < -87 (matches fp32 ref).
//
// R10: consolidate to the session-best structure (R1, 97us pass1): 256-thr
// blocks, 4 INDEPENDENT waves x 4 rows each, full-K sweep per wave, no
// block barriers in the loop, shuffle-only threshold tightening every 32
// k-iters. Session evidence: per-SIMD VALU-issue is ~40us in every variant;
// only stall time differs, and prefetch depth is the only variable that
// ever improved it (R1 batch-4 = 97; R9 depth-1 = 155; K-split/8-wave
// variants all >= 143). Changes vs R1:
//  (1) batch 4 -> 8 k-iters (A/B ping-pong): prefetch distance ~800cy of
//      own-issue vs ~200cy L2-hit latency. VGPR watch: (256,2) caps at 128;
//      WRITE_SIZE >> 4MB = spilled = revert.
//  (2) overflow/argmax-miss safety net inlined (R6): wave-parallel full-K
//      resweep (~5us) instead of the fixup kernel -> 3 launches, no cliff.
// bk[] precomputed in prep_cb + fmaf-chain dot -> f is bitwise identical at
// every site (R5 determinism lesson: inlined ||e||^2 + ffp-contract broke
// the x==0 argmax detection).

#define KCODES 16384
#define CAP 192

__device__ __forceinline__ float dot8s(const float (&z)[8], float4 c0,
                                       float4 c1, float b) {
    float a = fmaf(z[0], c0.x, b);
    a = fmaf(z[1], c0.y, a);
    a = fmaf(z[2], c0.z, a);
    a = fmaf(z[3], c0.w, a);
    a = fmaf(z[4], c1.x, a);
    a = fmaf(z[5], c1.y, a);
    a = fmaf(z[6], c1.z, a);
    a = fmaf(z[7], c1.w, a);
    return a;
}

// ---------------- prep: codebook norms + workspace zeroing ----------------
__global__ __launch_bounds__(256) void prep_cb(const float* __restrict__ cb,
                                               float* __restrict__ bk,
                                               float* __restrict__ avgp,
                                               float* __restrict__ scal) {
    int k = blockIdx.x * 256 + threadIdx.x;
    const float4* c4 = (const float4*)cb;
    float4 c0 = c4[2 * k], c1 = c4[2 * k + 1];
    float nrm = c0.x * c0.x + c0.y * c0.y + c0.z * c0.z + c0.w * c0.w
              + c1.x * c1.x + c1.y * c1.y + c1.z * c1.z + c1.w * c1.w;
    bk[k] = -100.0f * nrm;
    avgp[k] = 0.0f;              // ws is poisoned each launch: zero it here
    if (k < 8) scal[k] = 0.0f;
}

// ---------------- pass 1: 4 independent waves x 4 rows, full-K sweep -------
// Grid 512 blocks x 256 thr; wave w owns rows [16b + 4w, 16b + 4w + 4).
__global__ __launch_bounds__(256, 2) void pass1(
    const float* __restrict__ z, const float* __restrict__ cb,
    const float* __restrict__ bk, float* __restrict__ out_zq,
    float* __restrict__ out_idx, float* __restrict__ scal,
    float* __restrict__ avgp)
{
    __shared__ float wfb[16][CAP];
    __shared__ int   wkb[16][CAP];
    __shared__ int   cnt[16];
    __shared__ float redSq[4], redEnt[4];

    const int wave = threadIdx.x >> 6;
    const int lane = threadIdx.x & 63;
    const int w4 = wave * 4;
    const int row0 = blockIdx.x * 16 + w4;

    // load 4 rows (broadcast) and fold the 200x scale in (static idx only)
    float zr[4][8];
#pragma unroll
    for (int r = 0; r < 4; ++r) {
        int row = row0 + r;
        const float* p = z + (row >> 8) * 2048 + (row & 255);
#pragma unroll
        for (int c = 0; c < 8; ++c) zr[r][c] = 200.0f * p[c * 256];
    }
    if (threadIdx.x < 16) cnt[threadIdx.x] = 0;
    __syncthreads();

    const float4* c4 = (const float4*)cb;
    float m[4], mt[4];
#pragma unroll
    for (int r = 0; r < 4; ++r) m[r] = -3.4e38f;

    // warm-up: 512 codes, max only (threshold priming; re-swept below --
    // coverage must be total), then share across lanes
#pragma unroll
    for (int j = 0; j < 8; ++j) {
        int k = lane + 64 * j;
        float4 c0 = c4[2 * k], c1 = c4[2 * k + 1];
        float b = bk[k];
#pragma unroll
        for (int r = 0; r < 4; ++r) m[r] = fmaxf(m[r], dot8s(zr[r], c0, c1, b));
    }
#pragma unroll
    for (int off = 32; off; off >>= 1) {
#pragma unroll
        for (int r = 0; r < 4; ++r) m[r] = fmaxf(m[r], __shfl_xor(m[r], off));
    }
#pragma unroll
    for (int r = 0; r < 4; ++r) mt[r] = m[r] - 87.0f;

    // ---- main sweep: 32 batches x 8 k-iters, double-buffered prefetch ----
    float4 A0[8], A1[8]; float Ab[8];
    float4 B0[8], B1[8]; float Bb[8];

    auto loadA = [&](int bat) {
#pragma unroll
        for (int jj = 0; jj < 8; ++jj) {
            int k = lane + bat * 512 + 64 * jj;
            A0[jj] = c4[2 * k]; A1[jj] = c4[2 * k + 1]; Ab[jj] = bk[k];
        }
    };
    auto loadB = [&](int bat) {
#pragma unroll
        for (int jj = 0; jj < 8; ++jj) {
            int k = lane + bat * 512 + 64 * jj;
            B0[jj] = c4[2 * k]; B1[jj] = c4[2 * k + 1]; Bb[jj] = bk[k];
        }
    };
    // fast path per k: 32 FMA + 4 cmp; rare work behind wave-uniform __any
    auto comp = [&](int bat, const float4 (&P0)[8], const float4 (&P1)[8],
                    const float (&PB)[8]) {
#pragma unroll
        for (int jj = 0; jj < 8; ++jj) {
            float f0 = dot8s(zr[0], P0[jj], P1[jj], PB[jj]);
            float f1 = dot8s(zr[1], P0[jj], P1[jj], PB[jj]);
            float f2 = dot8s(zr[2], P0[jj], P1[jj], PB[jj]);
            float f3 = dot8s(zr[3], P0[jj], P1[jj], PB[jj]);
            bool h0 = f0 > mt[0], h1 = f1 > mt[1];
            bool h2 = f2 > mt[2], h3 = f3 > mt[3];
            if (__any(h0 | h1 | h2 | h3)) {      // wave-uniform, rare
                int k = lane + bat * 512 + 64 * jj;
                if (h0) { m[0] = fmaxf(m[0], f0); mt[0] = m[0] - 87.0f;
                    int s_ = atomicAdd(&cnt[w4 + 0], 1);
                    if (s_ < CAP) { wfb[w4 + 0][s_] = f0; wkb[w4 + 0][s_] = k; } }
                if (h1) { m[1] = fmaxf(m[1], f1); mt[1] = m[1] - 87.0f;
                    int s_ = atomicAdd(&cnt[w4 + 1], 1);
                    if (s_ < CAP) { wfb[w4 + 1][s_] = f1; wkb[w4 + 1][s_] = k; } }
                if (h2) { m[2] = fmaxf(m[2], f2); mt[2] = m[2] - 87.0f;
                    int s_ = atomicAdd(&cnt[w4 + 2], 1);
                    if (s_ < CAP) { wfb[w4 + 2][s_] = f2; wkb[w4 + 2][s_] = k; } }
                if (h3) { m[3] = fmaxf(m[3], f3); mt[3] = m[3] - 87.0f;
                    int s_ = atomicAdd(&cnt[w4 + 3], 1);
                    if (s_ < CAP) { wfb[w4 + 3][s_] = f3; wkb[w4 + 3][s_] = k; } }
            }
        }
    };

    loadA(0);                                    // prime the pipeline
#pragma unroll 1
    for (int t = 0; t < 8; ++t) {                // 8 super-blocks of 2048 codes
#pragma unroll 1
        for (int s = 0; s < 2; ++s) {
            const int b0 = t * 4 + s * 2;
            loadB(b0 + 1);                       // b0+1 <= 31: never wraps
            comp(b0, A0, A1, Ab);
            loadA((b0 + 2) & 31);                // t=7,s=1 wraps (harmless)
            comp(b0 + 1, B0, B1, Bb);
        }
        // tighten every lane's threshold to the wave-global running max
#pragma unroll
        for (int off = 32; off; off >>= 1) {
#pragma unroll
            for (int r = 0; r < 4; ++r)
                m[r] = fmaxf(m[r], __shfl_xor(m[r], off));
        }
#pragma unroll
        for (int r = 0; r < 4; ++r) mt[r] = m[r] - 87.0f;
    }
    __syncthreads();   // drain this wave's LDS atomics/writes before reads

    // flush: per row (statically unrolled -- rule #20: zr/m must not be
    // runtime-indexed), compute s, t, argmin, entropy, avg_probs
    float entAcc = 0.0f, sqAcc = 0.0f;
#pragma unroll
    for (int r = 0; r < 4; ++r) {
        const int br = w4 + r;
        const int row = row0 + r;
        const float mm = m[r];
        const int c = cnt[br];

        float sl = 0.0f, tl = 0.0f;
        int kmin = 0x7fffffff;
        bool ok = (c <= CAP);

        if (ok) {
            // ---- normal: stats from the recorded candidates ----
            for (int i = lane; i < c; i += 64) {
                float x = wfb[br][i] - mm;       // <= 0; == 0 at the argmax
                float e = 0.0f;
                if (x > -87.0f) {
                    e = __expf(x);
                    sl += e;
                    tl = fmaf(x, e, tl);
                    if (x == 0.0f) kmin = min(kmin, wkb[br][i]);
                }
                wfb[br][i] = e;                  // stash e for the avgp loop
            }
#pragma unroll
            for (int off = 32; off; off >>= 1) {
                sl += __shfl_xor(sl, off);
                tl += __shfl_xor(tl, off);
                kmin = min(kmin, __shfl_xor(kmin, off));
            }
            ok = (kmin != 0x7fffffff);           // argmax found? (safety net)
        }

        if (!ok) {
            // ---- overflow / argmax-miss: wave-parallel FULL-K resweep ----
            sl = 0.0f; tl = 0.0f; kmin = 0x7fffffff;
            for (int k = lane; k < KCODES; k += 64) {
                float f = dot8s(zr[r], c4[2 * k], c4[2 * k + 1], bk[k]);
                float x = f - mm;
                if (x > -87.0f) {
                    float e = __expf(x);
                    sl += e; tl = fmaf(x, e, tl);
                    if (x == 0.0f) kmin = min(kmin, k);
                }
            }
#pragma unroll
            for (int off = 32; off; off >>= 1) {
                sl += __shfl_xor(sl, off);
                tl += __shfl_xor(tl, off);
                kmin = min(kmin, __shfl_xor(kmin, off));
            }
            float rs = 1.0f / sl;
            for (int k = lane; k < KCODES; k += 64) {
                float f = dot8s(zr[r], c4[2 * k], c4[2 * k + 1], bk[k]);
                float x = f - mm;
                if (x > -87.0f) atomicAdd(&avgp[k], __expf(x) * rs);
            }
        } else {
            float rs = 1.0f / sl;
            for (int i = lane; i < c; i += 64) {
                float e = wfb[br][i];
                if (e != 0.0f) atomicAdd(&avgp[wkb[br][i]], e * rs);
            }
        }

        if (lane == 0) {
            float rs = 1.0f / sl;
            entAcc += tl * rs - logf(sl);
            out_idx[row] = (float)kmin;
            float4 q0 = c4[2 * kmin], q1 = c4[2 * kmin + 1];
            float qv[8] = {q0.x, q0.y, q0.z, q0.w, q1.x, q1.y, q1.z, q1.w};
            int bb = row >> 8, hw = row & 255;
            const float* zraw = z + bb * 2048 + hw;   // raw row (L1-hot)
            float* o = out_zq + bb * 2048 + hw;
#pragma unroll
            for (int ch = 0; ch < 8; ++ch) {
                float raw = zraw[ch * 256];
                o[ch * 256] = qv[ch];
                float dq = qv[ch] - raw;
                sqAcc += dq * dq;
            }
        }
    }
    if (lane == 0) { redSq[wave] = sqAcc; redEnt[wave] = entAcc; }
    __syncthreads();
    if (threadIdx.x == 0) {
        atomicAdd(&scal[0], redSq[0] + redSq[1] + redSq[2] + redSq[3]);
        atomicAdd(&scal[1], redEnt[0] + redEnt[1] + redEnt[2] + redEnt[3]);
    }
}

// ---------------- finalize: avg entropy + loss assembly ----------------
__global__ __launch_bounds__(256) void finalize(
    const float* __restrict__ avgp, const float* __restrict__ scal,
    float* __restrict__ out_loss)
{
    float acc = 0.0f;
    for (int k = threadIdx.x; k < KCODES; k += 256) {
        float avg = avgp[k] * (1.0f / 8192.0f);
        acc += avg * logf(avg + 1e-5f);    // avg==0 contributes exactly 0
    }
#pragma unroll
    for (int off = 32; off > 0; off >>= 1) acc += __shfl_xor(acc, off);
    __shared__ float red[4];
    int wave = threadIdx.x >> 6, lane = threadIdx.x & 63;
    if (lane == 0) red[wave] = acc;
    __syncthreads();
    if (threadIdx.x == 0) {
        float T = red[0] + red[1] + red[2] + red[3];   // sum avg*log(avg+eps)
        // loss = 1.25*mean((zq-z)^2) + 0.1*(sample_entropy - avg_entropy)
        float loss = 1.25f * (scal[0] * (1.0f / 65536.0f))
                   + 0.1f * (T - scal[1] * (1.0f / 8192.0f));
        out_loss[0] = loss;
    }
}

extern "C" void kernel_launch(void* const* d_in, const int* in_sizes, int n_in,
                              void* d_out, int out_size, void* d_ws, size_t ws_size,
                              hipStream_t stream) {
    const float* z  = (const float*)d_in[0];   // [32,8,16,16]
    const float* cb = (const float*)d_in[1];   // [16384,8]
    float* out = (float*)d_out;
    float* ws  = (float*)d_ws;

    // workspace layout (floats)
    float* bk   = ws;                // 16384 : -100*||e_k||^2
    float* avgp = ws + 16384;        // 16384 : sum_n p[n,k]
    float* scal = ws + 32768;        // 2     : [sq, entS]  (+6 pad)

    float* out_zq   = out;           // 65536
    float* out_loss = out + 65536;   // 1
    float* out_idx  = out + 65537;   // 8192

    // prep_cb zeroes avgp/scal (ws is re-poisoned every launch)
    prep_cb <<<64,  256, 0, stream>>>(cb, bk, avgp, scal);
    pass1   <<<512, 256, 0, stream>>>(z, cb, bk, out_zq, out_idx, scal, avgp);
    finalize<<<1,   256, 0, stream>>>(avgp, scal, out_loss);
}